// Round 1
// 687.381 us; speedup vs baseline: 1.2425x; 1.2425x over previous
//
#include <hip/hip_runtime.h>
#include <hip/hip_bf16.h>

#define N_NODES 40000
#define N_EDGES 300000
#define EMBED 256
#define CAP 64              // max in-degree per (node,dir); Poisson(7.5) tail => safe

typedef __attribute__((ext_vector_type(8))) short s16x8;   // 8 bf16 (4 VGPRs)
typedef __attribute__((ext_vector_type(4))) float f32x4;   // 4 fp32 acc

__device__ __forceinline__ float b2f(unsigned short u) {
    union { unsigned int i; float f; } v; v.i = ((unsigned int)u) << 16; return v.f;
}
__device__ __forceinline__ unsigned short f2b(float f) {   // fp32 -> bf16 RNE
    unsigned int x = __float_as_uint(f);
    x += 0x7fffu + ((x >> 16) & 1u);
    return (unsigned short)(x >> 16);
}
// int64 layout sniff (odd int32 words all zero) — insurance, contract says int32
__device__ __forceinline__ bool ht_is_i64(const int* __restrict__ ht) {
    int o = 0;
    #pragma unroll
    for (int k = 1; k < 16; k += 2) o |= ht[k];
    return o == 0;
}
__device__ __forceinline__ int clampN(int v) {
    unsigned u = (unsigned)v;
    return (u < N_NODES) ? v : 0;
}

// ---- fp32 -> bf16: H -> Hbf; Wf|Wb -> Wcat (256 rows x 1024 k) -------------
__global__ __launch_bounds__(256) void convert_kernel(
    const float* __restrict__ H, const float* __restrict__ Wf,
    const float* __restrict__ Wb,
    unsigned short* __restrict__ Hbf, unsigned short* __restrict__ Wcat)
{
    constexpr int NH4 = (N_NODES * EMBED) / 4;     // 2,560,000
    constexpr int NW4 = (EMBED * 2 * EMBED) / 4;   // 32,768 per W
    int ci = blockIdx.x * 256 + threadIdx.x;
    const float* src; unsigned short* dst;
    if (ci < NH4) {
        src = &H[(size_t)ci * 4]; dst = &Hbf[(size_t)ci * 4];
    } else if (ci < NH4 + NW4) {
        int j = (ci - NH4) * 4; int n = j >> 9, k = j & 511;
        src = &Wf[j]; dst = &Wcat[(size_t)n * 1024 + k];
    } else if (ci < NH4 + 2 * NW4) {
        int j = (ci - NH4 - NW4) * 4; int n = j >> 9, k = j & 511;
        src = &Wb[j]; dst = &Wcat[(size_t)n * 1024 + 512 + k];
    } else return;
    float4 v = *(const float4*)src;
    ushort4 o; o.x = f2b(v.x); o.y = f2b(v.y); o.z = f2b(v.z); o.w = f2b(v.w);
    *(ushort4*)dst = o;
}

// ---- build padded per-node edge lists (fwd keyed by tail, back by head) ----
__global__ __launch_bounds__(256) void build_kernel(
    const int* __restrict__ ht,
    int* __restrict__ cntf, int* __restrict__ cntb,
    int* __restrict__ listf, int* __restrict__ listb)
{
    int e = blockIdx.x * 256 + threadIdx.x;
    if (e >= N_EDGES) return;
    const bool wide = ht_is_i64(ht);
    int head = clampN(wide ? ht[(size_t)4 * e]     : ht[2 * e]);
    int tail = clampN(wide ? ht[(size_t)4 * e + 2] : ht[2 * e + 1]);
    int pf = atomicAdd(&cntf[tail], 1);
    if (pf < CAP) listf[tail * CAP + pf] = e;
    int pb = atomicAdd(&cntb[head], 1);
    if (pb < CAP) listb[head * CAP + pb] = e;
}

// ---- fused: gather-sum S (LDS, bf16) -> GEMM vs Wcat -> bias/mean/leaky/
// ---- residual/LayerNorm -> out. Block = 16 nodes, full 256-col rows. -------
// Gather restructured for latency: lane-parallel (e,nbr) preload into regs,
// readlane broadcast, 8-edge load groups (16 loads in flight per stall).
__global__ __launch_bounds__(256, 4) void fused_kernel(
    const unsigned short* __restrict__ Hbf, const float* __restrict__ E,
    const int* __restrict__ ht, const unsigned short* __restrict__ Wcat,
    const float* __restrict__ bf_, const float* __restrict__ bb_,
    const float* __restrict__ H, const float* __restrict__ lw,
    const float* __restrict__ lb,
    const int* __restrict__ cntf, const int* __restrict__ cntb,
    const int* __restrict__ listf, const int* __restrict__ listb,
    float* __restrict__ out)
{
    constexpr int LDK = 1032;                 // 1024 + 8 pad (keeps 16B align)
    __shared__ unsigned short S[16 * LDK];    // 33 KB
    __shared__ float stats[16][4][2];         // per-row per-wave (s, ss)

    const int tid  = threadIdx.x;
    const int wid  = tid >> 6;
    const int lane = tid & 63;
    const int q    = lane >> 4;
    const int c    = lane & 15;
    const int m0   = blockIdx.x * 16;
    const bool wide = ht_is_i64(ht);

    // ---- hoisted preloads: counts + edge lists + neighbor ids, all 4 nodes.
    // Lane t holds edge t of each (node, dir): one coalesced list load + one
    // per-lane ht gather replaces the per-edge dependent-load chain.
    int cF[4], cB[4];
    int eF[4], eB[4], nF[4], nB[4];
    #pragma unroll
    for (int i = 0; i < 4; i++) {
        const int node = m0 + wid * 4 + i;
        cF[i] = min(cntf[node], CAP);
        cB[i] = min(cntb[node], CAP);
    }
    #pragma unroll
    for (int i = 0; i < 4; i++) {
        const int node = m0 + wid * 4 + i;
        eF[i] = (lane < cF[i]) ? listf[node * CAP + lane] : 0;
        eB[i] = (lane < cB[i]) ? listb[node * CAP + lane] : 0;
    }
    #pragma unroll
    for (int i = 0; i < 4; i++) {
        nF[i] = clampN(wide ? ht[(size_t)4 * eF[i]]     : ht[2 * eF[i]]);      // head
        nB[i] = clampN(wide ? ht[(size_t)4 * eB[i] + 2] : ht[2 * eB[i] + 1]);  // tail
    }

    const int loff = lane * 4;

    // ---- gather phase: wave owns 4 nodes; 8-edge groups, weight-masked tail
    #pragma unroll
    for (int i = 0; i < 4; i++) {
        const int r = wid * 4 + i;
        float aHf[4] = {0.f,0.f,0.f,0.f}, aEf[4] = {0.f,0.f,0.f,0.f};
        float aHb[4] = {0.f,0.f,0.f,0.f}, aEb[4] = {0.f,0.f,0.f,0.f};

        for (int t = 0; t < cF[i]; t += 8) {
            float4 ev[8]; ushort4 hv[8]; float w[8];
            #pragma unroll
            for (int u = 0; u < 8; u++) {
                const int e  = __builtin_amdgcn_readlane(eF[i], t + u);
                const int nb = __builtin_amdgcn_readlane(nF[i], t + u);
                w[u] = (t + u < cF[i]) ? 1.0f : 0.0f;
                ev[u] = *(const float4*)(&E[(size_t)e * EMBED + loff]);
                hv[u] = *(const ushort4*)(&Hbf[(size_t)nb * EMBED + loff]);
            }
            #pragma unroll
            for (int u = 0; u < 8; u++) {
                aEf[0] += w[u] * ev[u].x; aEf[1] += w[u] * ev[u].y;
                aEf[2] += w[u] * ev[u].z; aEf[3] += w[u] * ev[u].w;
                aHf[0] += w[u] * b2f(hv[u].x); aHf[1] += w[u] * b2f(hv[u].y);
                aHf[2] += w[u] * b2f(hv[u].z); aHf[3] += w[u] * b2f(hv[u].w);
            }
        }
        for (int t = 0; t < cB[i]; t += 8) {
            float4 ev[8]; ushort4 hv[8]; float w[8];
            #pragma unroll
            for (int u = 0; u < 8; u++) {
                const int e  = __builtin_amdgcn_readlane(eB[i], t + u);
                const int nb = __builtin_amdgcn_readlane(nB[i], t + u);
                w[u] = (t + u < cB[i]) ? 1.0f : 0.0f;
                ev[u] = *(const float4*)(&E[(size_t)e * EMBED + loff]);
                hv[u] = *(const ushort4*)(&Hbf[(size_t)nb * EMBED + loff]);
            }
            #pragma unroll
            for (int u = 0; u < 8; u++) {
                aEb[0] += w[u] * ev[u].x; aEb[1] += w[u] * ev[u].y;
                aEb[2] += w[u] * ev[u].z; aEb[3] += w[u] * ev[u].w;
                aHb[0] += w[u] * b2f(hv[u].x); aHb[1] += w[u] * b2f(hv[u].y);
                aHb[2] += w[u] * b2f(hv[u].z); aHb[3] += w[u] * b2f(hv[u].w);
            }
        }

        // S row r = [ΣH_head | ΣE_fwd | ΣH_tail | ΣE_back] as bf16
        ushort4 o;
        o.x=f2b(aHf[0]); o.y=f2b(aHf[1]); o.z=f2b(aHf[2]); o.w=f2b(aHf[3]);
        *(ushort4*)(&S[r * LDK +   0 + loff]) = o;
        o.x=f2b(aEf[0]); o.y=f2b(aEf[1]); o.z=f2b(aEf[2]); o.w=f2b(aEf[3]);
        *(ushort4*)(&S[r * LDK + 256 + loff]) = o;
        o.x=f2b(aHb[0]); o.y=f2b(aHb[1]); o.z=f2b(aHb[2]); o.w=f2b(aHb[3]);
        *(ushort4*)(&S[r * LDK + 512 + loff]) = o;
        o.x=f2b(aEb[0]); o.y=f2b(aEb[1]); o.z=f2b(aEb[2]); o.w=f2b(aEb[3]);
        *(ushort4*)(&S[r * LDK + 768 + loff]) = o;
    }
    __syncthreads();

    // ---- GEMM: 16 x 1024 x 256, wave covers cols n0..n0+63 ----------------
    const int n0 = wid * 64;
    f32x4 acc[4];
    #pragma unroll
    for (int nt = 0; nt < 4; nt++) acc[nt] = (f32x4){0.f,0.f,0.f,0.f};

    #pragma unroll 4
    for (int k0 = 0; k0 < 1024; k0 += 32) {
        // A frag: A[m=c][k=q*8+j]
        s16x8 a = *(const s16x8*)(&S[c * LDK + k0 + q * 8]);
        #pragma unroll
        for (int nt = 0; nt < 4; nt++) {
            s16x8 b = *(const s16x8*)(&Wcat[(size_t)(n0 + nt * 16 + c) * 1024 + k0 + q * 8]);
            acc[nt] = __builtin_amdgcn_mfma_f32_16x16x32_bf16(a, b, acc[nt], 0, 0, 0);
        }
    }

    // ---- epilogue: bias, /count, leaky, +H, LayerNorm ----------------------
    float x[4][4];                 // [reg(row)][nt]
    float sr[4], ssr[4];
    #pragma unroll
    for (int reg = 0; reg < 4; reg++) {
        const int row  = q * 4 + reg;
        const int node = m0 + row;
        const float cf = (float)cntf[node];
        const float cb = (float)cntb[node];
        const float tot = cf + cb;
        const float inv = (tot > 0.f) ? (1.0f / tot) : 0.f;
        float s = 0.f, ss = 0.f;
        #pragma unroll
        for (int nt = 0; nt < 4; nt++) {
            const int j = n0 + nt * 16 + c;
            float v = acc[nt][reg] + cf * bf_[j] + cb * bb_[j];
            float m = v * inv;
            m = (m > 0.f) ? m : 0.01f * m;          // leaky_relu
            float xx = m + H[(size_t)node * EMBED + j];
            x[reg][nt] = xx; s += xx; ss += xx * xx;
        }
        sr[reg] = s; ssr[reg] = ss;
    }
    // reduce over the 16 c-lanes within each quad
    #pragma unroll
    for (int off = 1; off < 16; off <<= 1) {
        #pragma unroll
        for (int reg = 0; reg < 4; reg++) {
            sr[reg]  += __shfl_xor(sr[reg],  off);
            ssr[reg] += __shfl_xor(ssr[reg], off);
        }
    }
    if (c == 0) {
        #pragma unroll
        for (int reg = 0; reg < 4; reg++) {
            stats[q * 4 + reg][wid][0] = sr[reg];
            stats[q * 4 + reg][wid][1] = ssr[reg];
        }
    }
    __syncthreads();
    #pragma unroll
    for (int reg = 0; reg < 4; reg++) {
        const int row  = q * 4 + reg;
        const int node = m0 + row;
        float s  = stats[row][0][0] + stats[row][1][0] + stats[row][2][0] + stats[row][3][0];
        float ss = stats[row][0][1] + stats[row][1][1] + stats[row][2][1] + stats[row][3][1];
        const float mean = s * (1.0f / EMBED);
        float var = ss * (1.0f / EMBED) - mean * mean;
        var = var < 0.f ? 0.f : var;
        const float rstd = rsqrtf(var + 1e-5f);
        #pragma unroll
        for (int nt = 0; nt < 4; nt++) {
            const int j = n0 + nt * 16 + c;
            out[(size_t)node * EMBED + j] = (x[reg][nt] - mean) * rstd * lw[j] + lb[j];
        }
    }
}

extern "C" void kernel_launch(void* const* d_in, const int* in_sizes, int n_in,
                              void* d_out, int out_size, void* d_ws, size_t ws_size,
                              hipStream_t stream) {
    const float* H   = (const float*)d_in[0];
    const float* E   = (const float*)d_in[1];
    const int*   ht  = (const int*)d_in[2];
    const float* Wf  = (const float*)d_in[5];
    const float* bf_ = (const float*)d_in[6];
    const float* Wb  = (const float*)d_in[7];
    const float* bb_ = (const float*)d_in[8];
    const float* lw  = (const float*)d_in[9];
    const float* lb  = (const float*)d_in[10];
    float* out = (float*)d_out;

    // ws layout (~42 MB total)
    int* cntf  = (int*)d_ws;                       // 40960 ints
    int* cntb  = cntf + 40960;
    int* listf = cntb + 40960;                     // 40000*CAP ints
    int* listb = listf + N_NODES * CAP;
    unsigned short* Hbf  = (unsigned short*)(listb + N_NODES * CAP);  // 10.24M
    unsigned short* Wcat = Hbf + (size_t)N_NODES * EMBED;             // 262144

    hipMemsetAsync(d_ws, 0, 2 * 40960 * sizeof(int), stream);

    constexpr int NCHUNK = (N_NODES * EMBED + 2 * EMBED * 2 * EMBED) / 4;
    convert_kernel<<<(NCHUNK + 255) / 256, 256, 0, stream>>>(H, Wf, Wb, Hbf, Wcat);
    build_kernel<<<(N_EDGES + 255) / 256, 256, 0, stream>>>(ht, cntf, cntb, listf, listb);
    fused_kernel<<<N_NODES / 16, 256, 0, stream>>>(Hbf, E, ht, Wcat, bf_, bb_,
                                                   H, lw, lb, cntf, cntb,
                                                   listf, listb, out);
}